// Round 5
// baseline (167.665 us; speedup 1.0000x reference)
//
#include <hip/hip_runtime.h>
#include <hip/hip_bf16.h>

typedef __bf16 bf16x8 __attribute__((ext_vector_type(8)));
typedef float f32x4 __attribute__((ext_vector_type(4)));
typedef ushort us8 __attribute__((ext_vector_type(8)));

#define MFMA(a, b, c) __builtin_amdgcn_mfma_f32_16x16x32_bf16((a), (b), (c), 0, 0, 0)

static constexpr int T_LEN = 2048;
static constexpr int C_DIM = 1024;
static constexpr int H_DIM = 128;
static constexpr int M_ROWS = 8 * 2048;    // 16384
static constexpr int N_COLS = 384;         // 3 * 128

__device__ __forceinline__ ushort f2bf(float f) {
  union { float f; unsigned u; } v; v.f = f;
  unsigned u = v.u;
  u += 0x7fffu + ((u >> 16) & 1u);
  return (ushort)(u >> 16);
}
__device__ __forceinline__ float bf2f(ushort u) {
  union { unsigned u; float f; } v; v.u = (unsigned)u << 16;
  return v.f;
}

// ---------------------------------------------------------------------------
// Kernel 0: Wq/Wk/Wv fp32 [1024][128] -> bf16 Wt[384][1024] (transposed)
// ---------------------------------------------------------------------------
__global__ void wt_convert(const float* __restrict__ Wq,
                           const float* __restrict__ Wk,
                           const float* __restrict__ Wv,
                           ushort* __restrict__ wt) {
  int flat = blockIdx.x * 256 + threadIdx.x;
  int gc = flat >> 10;
  int c  = flat & 1023;
  int mat = gc >> 7;
  int h   = gc & 127;
  const float* W = (mat == 0) ? Wq : ((mat == 1) ? Wk : Wv);
  wt[flat] = f2bf(W[c * H_DIM + h]);
}

// ---------------------------------------------------------------------------
// Kernel 1: fused QKV projection. 2-phase double-buffered LDS template.
// 256 thr (4 waves), BM=32, BN=192 (N split x2) -> 1024 blocks, 4/CU.
// A tile bf16 in LDS, linear [32][128B] + XOR swizzle (row&7)<<4 (T2).
// Wave owns 48 cols. One barrier per K-iter (BK=64, 16 iters).
// ---------------------------------------------------------------------------
__global__ __launch_bounds__(256, 4) void qkv_gemm(const float* __restrict__ X,
                                                   const ushort* __restrict__ wt,
                                                   ushort* __restrict__ qws,
                                                   ushort* __restrict__ kws,
                                                   ushort* __restrict__ vtws) {
  __shared__ ushort As[2][32 * 64];
  const int tid = threadIdx.x;
  const int wid = tid >> 6, lane = tid & 63;
  const int lg = lane >> 4, lr = lane & 15;
  const int m0 = (blockIdx.x >> 1) * 32;
  const int n0 = (blockIdx.x & 1) * 192;

  // staging: thread -> (row = tid>>3, 8 floats at col (tid&7)*8)
  const int srow = tid >> 3;
  const int sbyte = ((tid & 7) * 16) ^ ((srow & 7) << 4);   // swizzled byte col
  const float* xrow = &X[(size_t)(m0 + srow) * C_DIM + (tid & 7) * 8];

  f32x4 acc[2][3];
#pragma unroll
  for (int r = 0; r < 2; ++r)
#pragma unroll
    for (int c = 0; c < 3; ++c)
      acc[r][c] = f32x4{0.f, 0.f, 0.f, 0.f};

  // prologue: stage tile 0
  {
    float4 x0 = *(const float4*)&xrow[0];
    float4 x1 = *(const float4*)&xrow[4];
    us8 bv;
    bv[0] = f2bf(x0.x); bv[1] = f2bf(x0.y); bv[2] = f2bf(x0.z); bv[3] = f2bf(x0.w);
    bv[4] = f2bf(x1.x); bv[5] = f2bf(x1.y); bv[6] = f2bf(x1.z); bv[7] = f2bf(x1.w);
    *(us8*)((char*)&As[0][0] + srow * 128 + sbyte) = bv;
  }

  for (int kt = 0; kt < 16; ++kt) {
    const int cur = kt & 1;
    float4 x0n, x1n;
    if (kt < 15) {
      x0n = *(const float4*)&xrow[(kt + 1) * 64];
      x1n = *(const float4*)&xrow[(kt + 1) * 64 + 4];
    }

    __syncthreads();

    bf16x8 a[2][2];
#pragma unroll
    for (int r = 0; r < 2; ++r)
#pragma unroll
      for (int ks = 0; ks < 2; ++ks) {
        int row = r * 16 + lr;
        int cb = (ks * 64 + lg * 16) ^ ((row & 7) << 4);
        a[r][ks] = *(const bf16x8*)((const char*)&As[cur][0] + row * 128 + cb);
      }

#pragma unroll
    for (int c = 0; c < 3; ++c) {
      int gc = n0 + wid * 48 + c * 16 + lr;
#pragma unroll
      for (int ks = 0; ks < 2; ++ks) {
        bf16x8 bfrag = *(const bf16x8*)&wt[(size_t)gc * C_DIM + kt * 64 + ks * 32 + lg * 8];
        acc[0][c] = MFMA(a[0][ks], bfrag, acc[0][c]);
        acc[1][c] = MFMA(a[1][ks], bfrag, acc[1][c]);
      }
    }

    if (kt < 15) {
      us8 bv;
      bv[0] = f2bf(x0n.x); bv[1] = f2bf(x0n.y); bv[2] = f2bf(x0n.z); bv[3] = f2bf(x0n.w);
      bv[4] = f2bf(x1n.x); bv[5] = f2bf(x1n.y); bv[6] = f2bf(x1n.z); bv[7] = f2bf(x1n.w);
      *(us8*)((char*)&As[cur ^ 1][0] + srow * 128 + sbyte) = bv;
    }
  }

  // epilogue: C frag layout col=lane&15, row=(lane>>4)*4+j
#pragma unroll
  for (int c = 0; c < 3; ++c) {
    int gc = n0 + wid * 48 + c * 16 + lr;
    int mat = gc >> 7, h = gc & 127;
#pragma unroll
    for (int r = 0; r < 2; ++r) {
#pragma unroll
      for (int j = 0; j < 4; ++j) {
        int gr = m0 + r * 16 + lg * 4 + j;
        ushort ov = f2bf(acc[r][c][j]);
        if (mat == 0) {
          qws[(size_t)gr * H_DIM + h] = ov;
        } else if (mat == 1) {
          kws[(size_t)gr * H_DIM + h] = ov;
        } else {
          int b = gr >> 11, t = gr & 2047;
          vtws[((size_t)b * H_DIM + h) * T_LEN + t] = ov;
        }
      }
    }
  }
}

// ---------------------------------------------------------------------------
// Kernel 2a: flash partial pass, per-wave Q-tiles.
// Block = (b, qb, ck): 64 q-rows; wave w owns 16-row q-tile qi=qb*4+w and
// iterates kv tiles ck*8 .. min(ck*8+8, qb+1). No cross-wave barriers.
// Exact grid: 8 batches x 80 chunk-items = 640 blocks (band decode).
// qb<8 (single chunk): normalize + write out directly. Else partial to ws.
// ---------------------------------------------------------------------------
__global__ __launch_bounds__(256, 4) void attn_part(const ushort* __restrict__ qws,
                                                    const ushort* __restrict__ kws,
                                                    const ushort* __restrict__ vtws,
                                                    float* __restrict__ pml,
                                                    ushort* __restrict__ pacc,
                                                    float* __restrict__ out) {
  __shared__ ushort Pl[4][16][72];

  const int tid = threadIdx.x;
  const int wid = tid >> 6, lane = tid & 63;
  const int lg = lane >> 4, lr = lane & 15;
  const int bid = blockIdx.x;
  const int b = bid & 7;               // batch pinned per XCD
  const int item = bid >> 3;           // 0..79
  const int t = (item >= 48) ? 3 : (item >= 24) ? 2 : (item >= 8) ? 1 : 0;
  const int bstart = (t == 3) ? 48 : (t == 2) ? 24 : (t == 1) ? 8 : 0;
  const int off = item - bstart;
  const int qb = 8 * t + off / (t + 1);
  const int ck = off - (off / (t + 1)) * (t + 1);
  const int qi = qb * 4 + wid;
  const int q0 = qi * 16;
  const int nt = qb + 1;
  const int kvt_lo = ck * 8;
  const int kvt_hi = min(kvt_lo + 8, nt);
  const size_t tokbase = (size_t)b * T_LEN;

  bf16x8 qf[4];
#pragma unroll
  for (int hk = 0; hk < 4; ++hk)
    qf[hk] = *(const bf16x8*)&qws[(tokbase + q0 + lr) * H_DIM + hk * 32 + lg * 8];

  f32x4 acc[8];
#pragma unroll
  for (int hf = 0; hf < 8; ++hf) acc[hf] = f32x4{0.f, 0.f, 0.f, 0.f};
  float mrun[4], lrun[4];
#pragma unroll
  for (int j = 0; j < 4; ++j) { mrun[j] = -INFINITY; lrun[j] = 0.f; }

  const float SCL = 0.03125f * 1.44269504f;   // C^-0.5 folded with log2(e)
  const ushort* vb = vtws + (size_t)b * H_DIM * T_LEN;

  for (int kvt = kvt_lo; kvt < kvt_hi; ++kvt) {
    const int kv0 = kvt * 64;

    // S = Q K^T  (16 q rows x 64 kv)
    f32x4 s[4];
#pragma unroll
    for (int c = 0; c < 4; ++c) {
      f32x4 sc = f32x4{0.f, 0.f, 0.f, 0.f};
#pragma unroll
      for (int hk = 0; hk < 4; ++hk) {
        bf16x8 kf = *(const bf16x8*)&kws[(tokbase + kv0 + c * 16 + lr) * H_DIM + hk * 32 + lg * 8];
        sc = MFMA(qf[hk], kf, sc);
      }
      s[c] = sc;
    }

    // scale + causal mask (diagonal tile only)
    if (kvt == nt - 1) {
#pragma unroll
      for (int c = 0; c < 4; ++c)
#pragma unroll
        for (int j = 0; j < 4; ++j) {
          int kv = kv0 + c * 16 + lr;
          int qr = q0 + lg * 4 + j;
          s[c][j] = (kv <= qr) ? s[c][j] * SCL : -INFINITY;
        }
    } else {
#pragma unroll
      for (int c = 0; c < 4; ++c)
#pragma unroll
        for (int j = 0; j < 4; ++j) s[c][j] *= SCL;
    }

    // row max across the 16-lane kv groups
    float mx[4];
#pragma unroll
    for (int j = 0; j < 4; ++j)
      mx[j] = fmaxf(fmaxf(s[0][j], s[1][j]), fmaxf(s[2][j], s[3][j]));
#pragma unroll
    for (int off2 = 8; off2 >= 1; off2 >>= 1)
#pragma unroll
      for (int j = 0; j < 4; ++j)
        mx[j] = fmaxf(mx[j], __shfl_xor(mx[j], off2));

    float mnew[4], scold[4];
#pragma unroll
    for (int j = 0; j < 4; ++j) {
      mnew[j] = fmaxf(mrun[j], mx[j]);
      scold[j] = exp2f(mrun[j] - mnew[j]);
    }

    // P = exp2(s - m), bf16 P to per-wave LDS (C-layout -> A-layout)
    float rsum[4] = {0.f, 0.f, 0.f, 0.f};
#pragma unroll
    for (int c = 0; c < 4; ++c)
#pragma unroll
      for (int j = 0; j < 4; ++j) {
        float p = exp2f(s[c][j] - mnew[j]);
        rsum[j] += p;
        Pl[wid][lg * 4 + j][c * 16 + lr] = f2bf(p);
      }

    // prefetch V f=0 slice (independent of softmax) to hide latency
    bf16x8 v0[8];
#pragma unroll
    for (int hf = 0; hf < 8; ++hf)
      v0[hf] = *(const bf16x8*)&vb[(size_t)(hf * 16 + lr) * T_LEN + kv0 + lg * 8];

#pragma unroll
    for (int off2 = 8; off2 >= 1; off2 >>= 1)
#pragma unroll
      for (int j = 0; j < 4; ++j) rsum[j] += __shfl_xor(rsum[j], off2);

#pragma unroll
    for (int j = 0; j < 4; ++j) {
      lrun[j] = lrun[j] * scold[j] + rsum[j];
      mrun[j] = mnew[j];
    }
#pragma unroll
    for (int hf = 0; hf < 8; ++hf)
#pragma unroll
      for (int j = 0; j < 4; ++j) acc[hf][j] *= scold[j];

    // read P as A fragments (within-wave LDS, no barrier)
    bf16x8 pa[2];
#pragma unroll
    for (int f = 0; f < 2; ++f)
      pa[f] = *(const bf16x8*)&Pl[wid][lr][f * 32 + lg * 8];

    // O += P V : f=0 uses prefetched v0; f=1 loads inline
#pragma unroll
    for (int hf = 0; hf < 8; ++hf)
      acc[hf] = MFMA(pa[0], v0[hf], acc[hf]);
#pragma unroll
    for (int hf = 0; hf < 8; ++hf) {
      bf16x8 v1 = *(const bf16x8*)&vb[(size_t)(hf * 16 + lr) * T_LEN + kv0 + 32 + lg * 8];
      acc[hf] = MFMA(pa[1], v1, acc[hf]);
    }
  }

  if (qb < 8) {
    // single chunk for this q-tile: write normalized output directly
#pragma unroll
    for (int j = 0; j < 4; ++j) {
      float inv = 1.0f / lrun[j];
      size_t row = (tokbase + q0 + lg * 4 + j) * H_DIM;
#pragma unroll
      for (int hf = 0; hf < 8; ++hf)
        out[row + hf * 16 + lr] = acc[hf][j] * inv;
    }
  } else {
    const size_t sidx = ((size_t)(b * 128 + qi)) * 4 + ck;
    if (lr == 0) {
#pragma unroll
      for (int j = 0; j < 4; ++j) {
        pml[sidx * 32 + lg * 4 + j] = mrun[j];
        pml[sidx * 32 + 16 + lg * 4 + j] = lrun[j];
      }
    }
#pragma unroll
    for (int j = 0; j < 4; ++j)
#pragma unroll
      for (int hf = 0; hf < 8; ++hf)
        pacc[sidx * 2048 + (size_t)(lg * 4 + j) * 128 + hf * 16 + lr] =
            f2bf(acc[hf][j]);
  }
}

// ---------------------------------------------------------------------------
// Kernel 2b: merge 2..4 partials per (b, qi) for qi >= 32. 768 blocks.
// ---------------------------------------------------------------------------
__global__ __launch_bounds__(256) void attn_merge(const float* __restrict__ pml,
                                                  const ushort* __restrict__ pacc,
                                                  float* __restrict__ out) {
  const int bid = blockIdx.x;
  const int b = bid & 7, qi = (bid >> 3) + 32;
  const int nch = (qi >> 5) + 1;       // 2..4
  const int tid = threadIdx.x;
  const int r = tid >> 4, c0 = (tid & 15) * 8;
  const size_t sbase = ((size_t)(b * 128 + qi)) * 4;

  float m_[4], l_[4];
  float mgl = -INFINITY;
#pragma unroll
  for (int ck = 0; ck < 4; ++ck) {
    bool act = ck < nch;
    m_[ck] = act ? pml[(sbase + ck) * 32 + r] : -INFINITY;
    l_[ck] = act ? pml[(sbase + ck) * 32 + 16 + r] : 0.f;
    mgl = fmaxf(mgl, m_[ck]);
  }
  float o[8];
#pragma unroll
  for (int i = 0; i < 8; ++i) o[i] = 0.f;
  float L = 0.f;
#pragma unroll
  for (int ck = 0; ck < 4; ++ck) {
    if (ck < nch) {
      float w = exp2f(m_[ck] - mgl);
      L += l_[ck] * w;
      const ushort* ap = &pacc[(sbase + ck) * 2048 + (size_t)r * 128 + c0];
      ushort4 u0 = *(const ushort4*)ap;
      ushort4 u1 = *(const ushort4*)(ap + 4);
      o[0] += w * bf2f(u0.x); o[1] += w * bf2f(u0.y);
      o[2] += w * bf2f(u0.z); o[3] += w * bf2f(u0.w);
      o[4] += w * bf2f(u1.x); o[5] += w * bf2f(u1.y);
      o[6] += w * bf2f(u1.z); o[7] += w * bf2f(u1.w);
    }
  }
  float invL = 1.0f / L;
  float4 r0 = make_float4(o[0] * invL, o[1] * invL, o[2] * invL, o[3] * invL);
  float4 r1 = make_float4(o[4] * invL, o[5] * invL, o[6] * invL, o[7] * invL);
  float* op = &out[((size_t)b * T_LEN + qi * 16 + r) * H_DIM + c0];
  *(float4*)op = r0;
  *(float4*)(op + 4) = r1;
}

// ---------------------------------------------------------------------------
extern "C" void kernel_launch(void* const* d_in, const int* in_sizes, int n_in,
                              void* d_out, int out_size, void* d_ws, size_t ws_size,
                              hipStream_t stream) {
  const float* emb = (const float*)d_in[0];
  const float* Wq  = (const float*)d_in[1];
  const float* Wk  = (const float*)d_in[2];
  const float* Wv  = (const float*)d_in[3];
  float* out = (float*)d_out;

  ushort* wt   = (ushort*)d_ws;                       // [384][1024] bf16
  ushort* qws  = wt  + (size_t)N_COLS * C_DIM;        // [16384][128] bf16
  ushort* kws  = qws + (size_t)M_ROWS * H_DIM;        // [16384][128] bf16
  ushort* vtws = kws + (size_t)M_ROWS * H_DIM;        // [8][128][2048] bf16
  float*  pml  = (float*)(vtws + (size_t)8 * H_DIM * T_LEN);  // [4096][32] f32
  ushort* pacc = (ushort*)(pml + (size_t)4096 * 32);          // [4096][2048] bf16

  wt_convert<<<(N_COLS * C_DIM) / 256, 256, 0, stream>>>(Wq, Wk, Wv, wt);
  qkv_gemm<<<(M_ROWS / 32) * 2, 256, 0, stream>>>(emb, wt, qws, kws, vtws);
  attn_part<<<640, 256, 0, stream>>>(qws, kws, vtws, pml, pacc, out);
  attn_merge<<<768, 256, 0, stream>>>(pml, pacc, out);
}

// Round 8
// 154.994 us; speedup vs baseline: 1.0817x; 1.0817x over previous
//
#include <hip/hip_runtime.h>
#include <hip/hip_bf16.h>

typedef __bf16 bf16x8 __attribute__((ext_vector_type(8)));
typedef float f32x4 __attribute__((ext_vector_type(4)));
typedef ushort us8 __attribute__((ext_vector_type(8)));

#define MFMA(a, b, c) __builtin_amdgcn_mfma_f32_16x16x32_bf16((a), (b), (c), 0, 0, 0)

static constexpr int T_LEN = 2048;
static constexpr int C_DIM = 1024;
static constexpr int H_DIM = 128;
static constexpr int M_ROWS = 8 * 2048;    // 16384
static constexpr int N_COLS = 384;         // 3 * 128
static constexpr int ITEMS_PER_B = 560;    // 32 direct (qi<32) + 528 partial chunks
static constexpr int SLOTS_PER_B = 528;    // partial slots (qi>=32 only)
static constexpr int PSTR = 72;            // P buffer row stride (>=64, 16B-aligned rows)

__device__ __forceinline__ ushort f2bf(float f) {
  union { float f; unsigned u; } v; v.f = f;
  unsigned u = v.u;
  u += 0x7fffu + ((u >> 16) & 1u);
  return (ushort)(u >> 16);
}
__device__ __forceinline__ float bf2f(ushort u) {
  union { unsigned u; float f; } v; v.u = (unsigned)u << 16;
  return v.f;
}

// ---------------------------------------------------------------------------
// Kernel 0: Wq/Wk/Wv fp32 [1024][128] -> bf16 Wt[384][1024] (transposed)
// ---------------------------------------------------------------------------
__global__ void wt_convert(const float* __restrict__ Wq,
                           const float* __restrict__ Wk,
                           const float* __restrict__ Wv,
                           ushort* __restrict__ wt) {
  int flat = blockIdx.x * 256 + threadIdx.x;
  int gc = flat >> 10;
  int c  = flat & 1023;
  int mat = gc >> 7;
  int h   = gc & 127;
  const float* W = (mat == 0) ? Wq : ((mat == 1) ? Wk : Wv);
  wt[flat] = f2bf(W[c * H_DIM + h]);
}

// ---------------------------------------------------------------------------
// Kernel 1: fused QKV projection. 2-phase double-buffered LDS template.
// 256 thr (4 waves), BM=32, BN=192 (N split x2) -> 1024 blocks.
// Softmax scale (C^-0.5 * log2e) folded into q at write time.
// ---------------------------------------------------------------------------
__global__ __launch_bounds__(256, 4) void qkv_gemm(const float* __restrict__ X,
                                                   const ushort* __restrict__ wt,
                                                   ushort* __restrict__ qws,
                                                   ushort* __restrict__ kws,
                                                   ushort* __restrict__ vtws) {
  __shared__ ushort As[2][32 * 64];
  const int tid = threadIdx.x;
  const int wid = tid >> 6, lane = tid & 63;
  const int lg = lane >> 4, lr = lane & 15;
  const int m0 = (blockIdx.x >> 1) * 32;
  const int n0 = (blockIdx.x & 1) * 192;
  const float QSCL = 0.03125f * 1.44269504f;

  const int srow = tid >> 3;
  const int sbyte = ((tid & 7) * 16) ^ ((srow & 7) << 4);
  const float* xrow = &X[(size_t)(m0 + srow) * C_DIM + (tid & 7) * 8];

  f32x4 acc[2][3];
#pragma unroll
  for (int r = 0; r < 2; ++r)
#pragma unroll
    for (int c = 0; c < 3; ++c)
      acc[r][c] = f32x4{0.f, 0.f, 0.f, 0.f};

  {
    float4 x0 = *(const float4*)&xrow[0];
    float4 x1 = *(const float4*)&xrow[4];
    us8 bv;
    bv[0] = f2bf(x0.x); bv[1] = f2bf(x0.y); bv[2] = f2bf(x0.z); bv[3] = f2bf(x0.w);
    bv[4] = f2bf(x1.x); bv[5] = f2bf(x1.y); bv[6] = f2bf(x1.z); bv[7] = f2bf(x1.w);
    *(us8*)((char*)&As[0][0] + srow * 128 + sbyte) = bv;
  }

  for (int kt = 0; kt < 16; ++kt) {
    const int cur = kt & 1;
    float4 x0n, x1n;
    if (kt < 15) {
      x0n = *(const float4*)&xrow[(kt + 1) * 64];
      x1n = *(const float4*)&xrow[(kt + 1) * 64 + 4];
    }

    __syncthreads();

    bf16x8 a[2][2];
#pragma unroll
    for (int r = 0; r < 2; ++r)
#pragma unroll
      for (int ks = 0; ks < 2; ++ks) {
        int row = r * 16 + lr;
        int cb = (ks * 64 + lg * 16) ^ ((row & 7) << 4);
        a[r][ks] = *(const bf16x8*)((const char*)&As[cur][0] + row * 128 + cb);
      }

#pragma unroll
    for (int c = 0; c < 3; ++c) {
      int gc = n0 + wid * 48 + c * 16 + lr;
#pragma unroll
      for (int ks = 0; ks < 2; ++ks) {
        bf16x8 bfrag = *(const bf16x8*)&wt[(size_t)gc * C_DIM + kt * 64 + ks * 32 + lg * 8];
        acc[0][c] = MFMA(a[0][ks], bfrag, acc[0][c]);
        acc[1][c] = MFMA(a[1][ks], bfrag, acc[1][c]);
      }
    }

    if (kt < 15) {
      us8 bv;
      bv[0] = f2bf(x0n.x); bv[1] = f2bf(x0n.y); bv[2] = f2bf(x0n.z); bv[3] = f2bf(x0n.w);
      bv[4] = f2bf(x1n.x); bv[5] = f2bf(x1n.y); bv[6] = f2bf(x1n.z); bv[7] = f2bf(x1n.w);
      *(us8*)((char*)&As[cur ^ 1][0] + srow * 128 + sbyte) = bv;
    }
  }

#pragma unroll
  for (int c = 0; c < 3; ++c) {
    int gc = n0 + wid * 48 + c * 16 + lr;
    int mat = gc >> 7, h = gc & 127;
#pragma unroll
    for (int r = 0; r < 2; ++r) {
#pragma unroll
      for (int j = 0; j < 4; ++j) {
        int gr = m0 + r * 16 + lg * 4 + j;
        float val = acc[r][c][j];
        ushort ov = f2bf(mat == 0 ? val * QSCL : val);
        if (mat == 0) {
          qws[(size_t)gr * H_DIM + h] = ov;
        } else if (mat == 1) {
          kws[(size_t)gr * H_DIM + h] = ov;
        } else {
          int b = gr >> 11, t = gr & 2047;
          vtws[((size_t)b * H_DIM + h) * T_LEN + t] = ov;
        }
      }
    }
  }
}

// ---------------------------------------------------------------------------
// Kernel 2a: flash partial pass. 256-thr blocks, 4 INDEPENDENT waves,
// wave = one item (no barriers). Item space per batch (560 items):
//   item < 32            : qi = item, all nt<=8 tiles in-wave, direct out.
//   item >= 32 (p=item-32): banded chunks of 4 kv tiles for qi>=32 ->
//                           partial (m,l,accT) to slot b*528 + p.
// Swapped QK^T (S^T = K·Q): lane owns one q-row -> scalar softmax state.
// P relayout via per-wave LDS [16 q][64 kv], row stride PSTR=72.
// ws layout proven <= round-4 footprint; pml overlaps dead wt region.
// ---------------------------------------------------------------------------
__global__ __launch_bounds__(256, 4) void attn_part(const ushort* __restrict__ qws,
                                                    const ushort* __restrict__ kws,
                                                    const ushort* __restrict__ vtws,
                                                    float* __restrict__ pml,
                                                    ushort* __restrict__ pacc,
                                                    float* __restrict__ out) {
  __shared__ ushort Pw[4][16 * PSTR];

  const int tid = threadIdx.x;
  const int wid = tid >> 6, lane = tid & 63;
  const int lg = lane >> 4, lr = lane & 15;
  const int bid = blockIdx.x;
  const int b = bid & 7;                         // batch pinned per XCD
  const int item = (bid >> 3) * 4 + wid;         // 0..559

  int qi, ck;
  bool direct;
  if (item < 32) {
    qi = item; ck = 0; direct = true;
  } else {
    const int p = item - 32;
    direct = false;
    if (p < 48)       { int q = p / 3;         qi = 32 + q;  ck = p - q * 3; }
    else if (p < 112) { int q = (p - 48) >> 2; qi = 48 + q;  ck = (p - 48) & 3; }
    else if (p < 192) { int q = (p - 112) / 5; qi = 64 + q;  ck = (p - 112) - q * 5; }
    else if (p < 288) { int q = (p - 192) / 6; qi = 80 + q;  ck = (p - 192) - q * 6; }
    else if (p < 400) { int q = (p - 288) / 7; qi = 96 + q;  ck = (p - 288) - q * 7; }
    else              { int q = (p - 400) >> 3; qi = 112 + q; ck = (p - 400) & 7; }
  }
  const int q0 = qi * 16;
  const int nt = (qi >> 2) + 1;
  const int kvt_lo = direct ? 0 : ck * 4;
  const int kvt_hi = direct ? nt : min(ck * 4 + 4, nt);
  const size_t tokbase = (size_t)b * T_LEN;

  // Q fragments as B-operand: col = lr = q row, k = lg*8+j
  bf16x8 qf[4];
#pragma unroll
  for (int hk = 0; hk < 4; ++hk)
    qf[hk] = *(const bf16x8*)&qws[(tokbase + q0 + lr) * H_DIM + hk * 32 + lg * 8];

  f32x4 acc[8];   // O^T: col = lr = q, row = h = hf*16 + lg*4 + j
#pragma unroll
  for (int hf = 0; hf < 8; ++hf) acc[hf] = f32x4{0.f, 0.f, 0.f, 0.f};
  float mrun = -INFINITY, lrun = 0.f;

  const ushort* vb = vtws + (size_t)b * H_DIM * T_LEN;
  ushort* Pme = &Pw[wid][0];

  for (int kvt = kvt_lo; kvt < kvt_hi; ++kvt) {
    const int kv0 = kvt * 64;

    // S^T = K Q : lane: q = lr, kv = c*16 + lg*4 + j
    f32x4 s[4];
#pragma unroll
    for (int c = 0; c < 4; ++c) {
      f32x4 sc = f32x4{0.f, 0.f, 0.f, 0.f};
#pragma unroll
      for (int hk = 0; hk < 4; ++hk) {
        bf16x8 kf = *(const bf16x8*)&kws[(tokbase + kv0 + c * 16 + lr) * H_DIM + hk * 32 + lg * 8];
        sc = MFMA(kf, qf[hk], sc);
      }
      s[c] = sc;
    }

    // causal mask (diagonal tile only; scale already folded into q)
    if (kvt == nt - 1) {
#pragma unroll
      for (int c = 0; c < 4; ++c)
#pragma unroll
        for (int j = 0; j < 4; ++j) {
          int kv = kv0 + c * 16 + lg * 4 + j;
          if (kv > q0 + lr) s[c][j] = -INFINITY;
        }
    }

    // row max: 16 in-lane values + 2 cross-group shuffles
    float mx = s[0][0];
#pragma unroll
    for (int c = 0; c < 4; ++c)
#pragma unroll
      for (int j = 0; j < 4; ++j) mx = fmaxf(mx, s[c][j]);
    mx = fmaxf(mx, __shfl_xor(mx, 16));
    mx = fmaxf(mx, __shfl_xor(mx, 32));

    float mnew = fmaxf(mrun, mx);
    float scold = exp2f(mrun - mnew);

    float rsum = 0.f;
#pragma unroll
    for (int c = 0; c < 4; ++c)
#pragma unroll
      for (int j = 0; j < 4; ++j) {
        float p = exp2f(s[c][j] - mnew);
        s[c][j] = p;
        rsum += p;
      }

    // P to LDS: row q=lr, cols c*16+lg*4..+3  (ds_write_b64)
#pragma unroll
    for (int c = 0; c < 4; ++c) {
      ushort4 u;
      u.x = f2bf(s[c][0]); u.y = f2bf(s[c][1]);
      u.z = f2bf(s[c][2]); u.w = f2bf(s[c][3]);
      *(ushort4*)&Pme[lr * PSTR + c * 16 + lg * 4] = u;
    }

    // prefetch V ks=0 fragments while softmax finishes
    bf16x8 v0[8];
#pragma unroll
    for (int hf = 0; hf < 8; ++hf)
      v0[hf] = *(const bf16x8*)&vb[(size_t)(hf * 16 + lr) * T_LEN + kv0 + lg * 8];

    rsum += __shfl_xor(rsum, 16);
    rsum += __shfl_xor(rsum, 32);

    lrun = lrun * scold + rsum;
    mrun = mnew;
#pragma unroll
    for (int hf = 0; hf < 8; ++hf)
#pragma unroll
      for (int j = 0; j < 4; ++j) acc[hf][j] *= scold;

    // read P as B fragments: col q=lr, k = ks*32 + lg*8 + j
    bf16x8 pa0 = *(const bf16x8*)&Pme[lr * PSTR + lg * 8];
    bf16x8 pa1 = *(const bf16x8*)&Pme[lr * PSTR + 32 + lg * 8];

    // O^T += V^T P^T  (A = V^T rows h, B = P^T)
#pragma unroll
    for (int hf = 0; hf < 8; ++hf)
      acc[hf] = MFMA(v0[hf], pa0, acc[hf]);
#pragma unroll
    for (int hf = 0; hf < 8; ++hf) {
      bf16x8 v1 = *(const bf16x8*)&vb[(size_t)(hf * 16 + lr) * T_LEN + kv0 + 32 + lg * 8];
      acc[hf] = MFMA(v1, pa1, acc[hf]);
    }
  }

  if (direct) {
    // normalized output directly; row q0+lr, cols h
    float inv = 1.0f / lrun;
    float* op = &out[(tokbase + q0 + lr) * H_DIM + lg * 4];
#pragma unroll
    for (int hf = 0; hf < 8; ++hf) {
      float4 r0 = make_float4(acc[hf][0] * inv, acc[hf][1] * inv,
                              acc[hf][2] * inv, acc[hf][3] * inv);
      *(float4*)(op + hf * 16) = r0;
    }
  } else {
    const size_t slot = (size_t)b * SLOTS_PER_B + (item - 32);
    if (lg == 0) {
      pml[slot * 32 + lr] = mrun;
      pml[slot * 32 + 16 + lr] = lrun;
    }
    ushort* ap = &pacc[slot * 2048 + (size_t)lr * 128 + lg * 4];
#pragma unroll
    for (int hf = 0; hf < 8; ++hf) {
      ushort4 u;
      u.x = f2bf(acc[hf][0]); u.y = f2bf(acc[hf][1]);
      u.z = f2bf(acc[hf][2]); u.w = f2bf(acc[hf][3]);
      *(ushort4*)(ap + hf * 16) = u;
    }
  }
}

// ---------------------------------------------------------------------------
// Kernel 2b: online merge of 3..8 partials per (b, qi) for qi >= 32.
// 768 blocks x 256 thr; thread -> (row r=tid>>4, 8 cols at (tid&15)*8).
// ---------------------------------------------------------------------------
__global__ __launch_bounds__(256) void attn_merge(const float* __restrict__ pml,
                                                  const ushort* __restrict__ pacc,
                                                  float* __restrict__ out) {
  const int bid = blockIdx.x;
  const int b = bid & 7, qi = (bid >> 3) + 32;
  int base, nch;
  if (qi < 48)       { base = (qi - 32) * 3;        nch = 3; }
  else if (qi < 64)  { base = 48 + (qi - 48) * 4;   nch = 4; }
  else if (qi < 80)  { base = 112 + (qi - 64) * 5;  nch = 5; }
  else if (qi < 96)  { base = 192 + (qi - 80) * 6;  nch = 6; }
  else if (qi < 112) { base = 288 + (qi - 96) * 7;  nch = 7; }
  else               { base = 400 + (qi - 112) * 8; nch = 8; }
  const size_t slot0 = (size_t)b * SLOTS_PER_B + base;
  const int tid = threadIdx.x;
  const int r = tid >> 4, c0 = (tid & 15) * 8;

  float mrun = -INFINITY, L = 0.f;
  float o[8];
#pragma unroll
  for (int i = 0; i < 8; ++i) o[i] = 0.f;

  for (int ck = 0; ck < nch; ++ck) {
    const size_t s = slot0 + ck;
    float m = pml[s * 32 + r];
    float l = pml[s * 32 + 16 + r];
    float mn = fmaxf(mrun, m);
    float sc = exp2f(mrun - mn);
    float w  = exp2f(m - mn);
    L = L * sc + w * l;
    const ushort* ap = &pacc[s * 2048 + (size_t)r * 128 + c0];
    ushort4 u0 = *(const ushort4*)ap;
    ushort4 u1 = *(const ushort4*)(ap + 4);
    o[0] = o[0] * sc + w * bf2f(u0.x); o[1] = o[1] * sc + w * bf2f(u0.y);
    o[2] = o[2] * sc + w * bf2f(u0.z); o[3] = o[3] * sc + w * bf2f(u0.w);
    o[4] = o[4] * sc + w * bf2f(u1.x); o[5] = o[5] * sc + w * bf2f(u1.y);
    o[6] = o[6] * sc + w * bf2f(u1.z); o[7] = o[7] * sc + w * bf2f(u1.w);
    mrun = mn;
  }
  float invL = 1.0f / L;
  float4 r0 = make_float4(o[0] * invL, o[1] * invL, o[2] * invL, o[3] * invL);
  float4 r1 = make_float4(o[4] * invL, o[5] * invL, o[6] * invL, o[7] * invL);
  float* op = &out[((size_t)b * T_LEN + qi * 16 + r) * H_DIM + c0];
  *(float4*)op = r0;
  *(float4*)(op + 4) = r1;
}

// ---------------------------------------------------------------------------
// ws layout (bytes), total = 30,670,848 (== proven round-4 footprint):
//   [0,        786432)  wt   (dead after qkv_gemm)  -- pml overlaps here
//   [786432, 4980736)   qws
//   [4980736, 9175040)  kws
//   [9175040, 13369344) vtws
//   [13369344, 30670848) pacc  (8 * 528 slots * 2048 bf16)
//   pml = (float*)d_ws: 8*528*32*4 = 540,672 B <= 786,432 B  (fits in wt)
// ---------------------------------------------------------------------------
extern "C" void kernel_launch(void* const* d_in, const int* in_sizes, int n_in,
                              void* d_out, int out_size, void* d_ws, size_t ws_size,
                              hipStream_t stream) {
  const float* emb = (const float*)d_in[0];
  const float* Wq  = (const float*)d_in[1];
  const float* Wk  = (const float*)d_in[2];
  const float* Wv  = (const float*)d_in[3];
  float* out = (float*)d_out;

  ushort* wt   = (ushort*)d_ws;                       // [384][1024] bf16
  ushort* qws  = wt  + (size_t)N_COLS * C_DIM;        // [16384][128] bf16 (pre-scaled)
  ushort* kws  = qws + (size_t)M_ROWS * H_DIM;        // [16384][128] bf16
  ushort* vtws = kws + (size_t)M_ROWS * H_DIM;        // [8][128][2048] bf16
  ushort* pacc = vtws + (size_t)8 * H_DIM * T_LEN;    // [8*528][2048] bf16
  float*  pml  = (float*)d_ws;                        // overlaps wt (disjoint lifetime)

  wt_convert<<<(N_COLS * C_DIM) / 256, 256, 0, stream>>>(Wq, Wk, Wv, wt);
  qkv_gemm<<<(M_ROWS / 32) * 2, 256, 0, stream>>>(emb, wt, qws, kws, vtws);
  attn_part<<<8 * (ITEMS_PER_B / 4), 256, 0, stream>>>(qws, kws, vtws, pml, pacc, out);
  attn_merge<<<8 * 96, 256, 0, stream>>>(pml, pacc, out);
}

// Round 9
// 100.918 us; speedup vs baseline: 1.6614x; 1.5358x over previous
//
#include <hip/hip_runtime.h>
#include <hip/hip_bf16.h>

typedef __bf16 bf16x8 __attribute__((ext_vector_type(8)));
typedef float f32x4 __attribute__((ext_vector_type(4)));
typedef ushort us8 __attribute__((ext_vector_type(8)));

#define MFMA(a, b, c) __builtin_amdgcn_mfma_f32_16x16x32_bf16((a), (b), (c), 0, 0, 0)

static constexpr int T_LEN = 2048;
static constexpr int C_DIM = 1024;
static constexpr int H_DIM = 128;
static constexpr int M_ROWS = 8 * 2048;    // 16384
static constexpr int N_COLS = 384;         // 3 * 128
static constexpr int SLOTS_PER_B = 528;    // partial slots (qi>=32), same as round 8
static constexpr int PSTR = 72;            // P buffer row stride
static constexpr int KSTR = 136;           // K LDS row stride (272B, 2-way max)
static constexpr int VSTR = 72;            // V LDS row stride (144B, 2-way max)

__device__ __forceinline__ ushort f2bf(float f) {
  union { float f; unsigned u; } v; v.f = f;
  unsigned u = v.u;
  u += 0x7fffu + ((u >> 16) & 1u);
  return (ushort)(u >> 16);
}
__device__ __forceinline__ float bf2f(ushort u) {
  union { unsigned u; float f; } v; v.u = (unsigned)u << 16;
  return v.f;
}

// ---------------------------------------------------------------------------
// Kernel 0: Wq/Wk/Wv fp32 [1024][128] -> bf16 Wt[384][1024] (transposed)
// ---------------------------------------------------------------------------
__global__ void wt_convert(const float* __restrict__ Wq,
                           const float* __restrict__ Wk,
                           const float* __restrict__ Wv,
                           ushort* __restrict__ wt) {
  int flat = blockIdx.x * 256 + threadIdx.x;
  int gc = flat >> 10;
  int c  = flat & 1023;
  int mat = gc >> 7;
  int h   = gc & 127;
  const float* W = (mat == 0) ? Wq : ((mat == 1) ? Wk : Wv);
  wt[flat] = f2bf(W[c * H_DIM + h]);
}

// ---------------------------------------------------------------------------
// Kernel 1: fused QKV projection (unchanged from round 8).
// ---------------------------------------------------------------------------
__global__ __launch_bounds__(256, 4) void qkv_gemm(const float* __restrict__ X,
                                                   const ushort* __restrict__ wt,
                                                   ushort* __restrict__ qws,
                                                   ushort* __restrict__ kws,
                                                   ushort* __restrict__ vtws) {
  __shared__ ushort As[2][32 * 64];
  const int tid = threadIdx.x;
  const int wid = tid >> 6, lane = tid & 63;
  const int lg = lane >> 4, lr = lane & 15;
  const int m0 = (blockIdx.x >> 1) * 32;
  const int n0 = (blockIdx.x & 1) * 192;
  const float QSCL = 0.03125f * 1.44269504f;

  const int srow = tid >> 3;
  const int sbyte = ((tid & 7) * 16) ^ ((srow & 7) << 4);
  const float* xrow = &X[(size_t)(m0 + srow) * C_DIM + (tid & 7) * 8];

  f32x4 acc[2][3];
#pragma unroll
  for (int r = 0; r < 2; ++r)
#pragma unroll
    for (int c = 0; c < 3; ++c)
      acc[r][c] = f32x4{0.f, 0.f, 0.f, 0.f};

  {
    float4 x0 = *(const float4*)&xrow[0];
    float4 x1 = *(const float4*)&xrow[4];
    us8 bv;
    bv[0] = f2bf(x0.x); bv[1] = f2bf(x0.y); bv[2] = f2bf(x0.z); bv[3] = f2bf(x0.w);
    bv[4] = f2bf(x1.x); bv[5] = f2bf(x1.y); bv[6] = f2bf(x1.z); bv[7] = f2bf(x1.w);
    *(us8*)((char*)&As[0][0] + srow * 128 + sbyte) = bv;
  }

  for (int kt = 0; kt < 16; ++kt) {
    const int cur = kt & 1;
    float4 x0n, x1n;
    if (kt < 15) {
      x0n = *(const float4*)&xrow[(kt + 1) * 64];
      x1n = *(const float4*)&xrow[(kt + 1) * 64 + 4];
    }

    __syncthreads();

    bf16x8 a[2][2];
#pragma unroll
    for (int r = 0; r < 2; ++r)
#pragma unroll
      for (int ks = 0; ks < 2; ++ks) {
        int row = r * 16 + lr;
        int cb = (ks * 64 + lg * 16) ^ ((row & 7) << 4);
        a[r][ks] = *(const bf16x8*)((const char*)&As[cur][0] + row * 128 + cb);
      }

#pragma unroll
    for (int c = 0; c < 3; ++c) {
      int gc = n0 + wid * 48 + c * 16 + lr;
#pragma unroll
      for (int ks = 0; ks < 2; ++ks) {
        bf16x8 bfrag = *(const bf16x8*)&wt[(size_t)gc * C_DIM + kt * 64 + ks * 32 + lg * 8];
        acc[0][c] = MFMA(a[0][ks], bfrag, acc[0][c]);
        acc[1][c] = MFMA(a[1][ks], bfrag, acc[1][c]);
      }
    }

    if (kt < 15) {
      us8 bv;
      bv[0] = f2bf(x0n.x); bv[1] = f2bf(x0n.y); bv[2] = f2bf(x0n.z); bv[3] = f2bf(x0n.w);
      bv[4] = f2bf(x1n.x); bv[5] = f2bf(x1n.y); bv[6] = f2bf(x1n.z); bv[7] = f2bf(x1n.w);
      *(us8*)((char*)&As[cur ^ 1][0] + srow * 128 + sbyte) = bv;
    }
  }

#pragma unroll
  for (int c = 0; c < 3; ++c) {
    int gc = n0 + wid * 48 + c * 16 + lr;
    int mat = gc >> 7, h = gc & 127;
#pragma unroll
    for (int r = 0; r < 2; ++r) {
#pragma unroll
      for (int j = 0; j < 4; ++j) {
        int gr = m0 + r * 16 + lg * 4 + j;
        float val = acc[r][c][j];
        ushort ov = f2bf(mat == 0 ? val * QSCL : val);
        if (mat == 0) {
          qws[(size_t)gr * H_DIM + h] = ov;
        } else if (mat == 1) {
          kws[(size_t)gr * H_DIM + h] = ov;
        } else {
          int b = gr >> 11, t = gr & 2047;
          vtws[((size_t)b * H_DIM + h) * T_LEN + t] = ov;
        }
      }
    }
  }
}

// ---------------------------------------------------------------------------
// Kernel 2a: flash partial pass, BLOCK-COOPERATIVE LDS-staged K/V.
// Block = (b, qb, ck): 64 q rows (4 waves x 16), chunk of kv tiles.
//   qb < 8 : single chunk covers all nt=qb+1 tiles -> direct out.
//   qb >= 8: chunks of 4 tiles -> partial slot (same slot space as before).
// Per iteration: coalesced stage K[64x128], V^T[128x64] into LDS (reg
// prefetch for next tile issued between barriers); waves read frags from
// LDS. Swapped QK^T softmax identical to round 8.
// Grid: 8 batches x 140 items = 1120 blocks x 256 thr.
// ---------------------------------------------------------------------------
__global__ __launch_bounds__(256, 3) void attn_part(const ushort* __restrict__ qws,
                                                    const ushort* __restrict__ kws,
                                                    const ushort* __restrict__ vtws,
                                                    float* __restrict__ pml,
                                                    ushort* __restrict__ pacc,
                                                    float* __restrict__ out) {
  __shared__ ushort Klds[64 * KSTR];   // 17408 B
  __shared__ ushort Vlds[128 * VSTR];  // 18432 B
  __shared__ ushort Pw[4][16 * PSTR];  //  9216 B

  const int tid = threadIdx.x;
  const int wid = tid >> 6, lane = tid & 63;
  const int lg = lane >> 4, lr = lane & 15;
  const int bid = blockIdx.x;
  const int b = bid & 7;               // batch pinned per XCD
  const int item = bid >> 3;           // 0..139

  int qb, ck;
  bool direct;
  if (item < 8) {
    qb = item; ck = 0; direct = true;
  } else {
    const int p = item - 8;            // 0..131
    direct = false;
    if (p < 12)      { int q = p / 3;        qb = 8 + q;  ck = p - q * 3; }
    else if (p < 28) { int q = (p - 12) >> 2; qb = 12 + q; ck = (p - 12) & 3; }
    else if (p < 48) { int q = (p - 28) / 5; qb = 16 + q; ck = (p - 28) - q * 5; }
    else if (p < 72) { int q = (p - 48) / 6; qb = 20 + q; ck = (p - 48) - q * 6; }
    else if (p < 100){ int q = (p - 72) / 7; qb = 24 + q; ck = (p - 72) - q * 7; }
    else             { int q = (p - 100) >> 3; qb = 28 + q; ck = (p - 100) & 7; }
  }
  const int qi = qb * 4 + wid;         // per-wave 16-row q tile
  const int q0 = qi * 16;
  const int nt = qb + 1;               // block-level kv tiles (causal)
  const int kvt_lo = direct ? 0 : ck * 4;
  const int kvt_hi = direct ? nt : min(ck * 4 + 4, nt);
  const size_t tokbase = (size_t)b * T_LEN;
  const ushort* vb = vtws + (size_t)b * H_DIM * T_LEN;

  // staging mapping (coalesced): K row t>>2, 32-col seg t&3 ; V row t>>1, seg t&1
  const int kr = tid >> 2, kseg = tid & 3;
  const int vr = tid >> 1, vseg = tid & 1;
  const ushort* gK = &kws[(tokbase + kr) * H_DIM + kseg * 32];
  const ushort* gV = &vb[(size_t)vr * T_LEN + vseg * 32];

  // Q fragments as B-operand: col = lr = q row, k = lg*8+j
  bf16x8 qf[4];
#pragma unroll
  for (int hk = 0; hk < 4; ++hk)
    qf[hk] = *(const bf16x8*)&qws[(tokbase + q0 + lr) * H_DIM + hk * 32 + lg * 8];

  f32x4 acc[8];   // O^T: col = lr = q, row = h = hf*16 + lg*4 + j
#pragma unroll
  for (int hf = 0; hf < 8; ++hf) acc[hf] = f32x4{0.f, 0.f, 0.f, 0.f};
  float mrun = -INFINITY, lrun = 0.f;

  ushort* Pme = &Pw[wid][0];

  // prologue: load first tile into regs
  us8 kreg[4], vreg[4];
#pragma unroll
  for (int i = 0; i < 4; ++i) {
    kreg[i] = *(const us8*)(gK + (size_t)kvt_lo * 64 * H_DIM + i * 8);
    vreg[i] = *(const us8*)(gV + kvt_lo * 64 + i * 8);
  }

  for (int kvt = kvt_lo; kvt < kvt_hi; ++kvt) {
    const int kv0 = kvt * 64;

    __syncthreads();   // all waves done reading LDS from previous iter
#pragma unroll
    for (int i = 0; i < 4; ++i) {
      *(us8*)&Klds[kr * KSTR + kseg * 32 + i * 8] = kreg[i];
      *(us8*)&Vlds[vr * VSTR + vseg * 32 + i * 8] = vreg[i];
    }
    if (kvt + 1 < kvt_hi) {
#pragma unroll
      for (int i = 0; i < 4; ++i) {
        kreg[i] = *(const us8*)(gK + (size_t)(kv0 + 64) * H_DIM + i * 8);
        vreg[i] = *(const us8*)(gV + kv0 + 64 + i * 8);
      }
    }
    __syncthreads();   // staged tile visible

    // S^T = K Q : lane: q = lr, kv = c*16 + lg*4 + j   (K from LDS)
    f32x4 s[4];
#pragma unroll
    for (int c = 0; c < 4; ++c) {
      f32x4 sc = f32x4{0.f, 0.f, 0.f, 0.f};
#pragma unroll
      for (int hk = 0; hk < 4; ++hk) {
        bf16x8 kf = *(const bf16x8*)&Klds[(c * 16 + lr) * KSTR + hk * 32 + lg * 8];
        sc = MFMA(kf, qf[hk], sc);
      }
      s[c] = sc;
    }

    // causal mask (block's last tile is every wave's diagonal tile)
    if (kvt == nt - 1) {
#pragma unroll
      for (int c = 0; c < 4; ++c)
#pragma unroll
        for (int j = 0; j < 4; ++j) {
          int kv = kv0 + c * 16 + lg * 4 + j;
          if (kv > q0 + lr) s[c][j] = -INFINITY;
        }
    }

    // row max: 16 in-lane values + 2 cross-group shuffles
    float mx = s[0][0];
#pragma unroll
    for (int c = 0; c < 4; ++c)
#pragma unroll
      for (int j = 0; j < 4; ++j) mx = fmaxf(mx, s[c][j]);
    mx = fmaxf(mx, __shfl_xor(mx, 16));
    mx = fmaxf(mx, __shfl_xor(mx, 32));

    float mnew = fmaxf(mrun, mx);
    float scold = exp2f(mrun - mnew);

    float rsum = 0.f;
#pragma unroll
    for (int c = 0; c < 4; ++c)
#pragma unroll
      for (int j = 0; j < 4; ++j) {
        float p = exp2f(s[c][j] - mnew);
        s[c][j] = p;
        rsum += p;
      }

    // P to per-wave LDS: row q=lr, cols c*16+lg*4..+3
#pragma unroll
    for (int c = 0; c < 4; ++c) {
      ushort4 u;
      u.x = f2bf(s[c][0]); u.y = f2bf(s[c][1]);
      u.z = f2bf(s[c][2]); u.w = f2bf(s[c][3]);
      *(ushort4*)&Pme[lr * PSTR + c * 16 + lg * 4] = u;
    }

    // V ks=0 fragments from LDS while softmax finishes
    bf16x8 v0[8];
#pragma unroll
    for (int hf = 0; hf < 8; ++hf)
      v0[hf] = *(const bf16x8*)&Vlds[(hf * 16 + lr) * VSTR + lg * 8];

    rsum += __shfl_xor(rsum, 16);
    rsum += __shfl_xor(rsum, 32);

    lrun = lrun * scold + rsum;
    mrun = mnew;
#pragma unroll
    for (int hf = 0; hf < 8; ++hf)
#pragma unroll
      for (int j = 0; j < 4; ++j) acc[hf][j] *= scold;

    // read P as B fragments: col q=lr, k = ks*32 + lg*8 + j
    bf16x8 pa0 = *(const bf16x8*)&Pme[lr * PSTR + lg * 8];
    bf16x8 pa1 = *(const bf16x8*)&Pme[lr * PSTR + 32 + lg * 8];

    // O^T += V^T P^T
#pragma unroll
    for (int hf = 0; hf < 8; ++hf)
      acc[hf] = MFMA(v0[hf], pa0, acc[hf]);
#pragma unroll
    for (int hf = 0; hf < 8; ++hf) {
      bf16x8 v1 = *(const bf16x8*)&Vlds[(hf * 16 + lr) * VSTR + 32 + lg * 8];
      acc[hf] = MFMA(v1, pa1, acc[hf]);
    }
  }

  if (direct) {
    float inv = 1.0f / lrun;
    float* op = &out[(tokbase + q0 + lr) * H_DIM + lg * 4];
#pragma unroll
    for (int hf = 0; hf < 8; ++hf) {
      float4 r0 = make_float4(acc[hf][0] * inv, acc[hf][1] * inv,
                              acc[hf][2] * inv, acc[hf][3] * inv);
      *(float4*)(op + hf * 16) = r0;
    }
  } else {
    // slot base identical to round-8 mapping (qi >= 32 guaranteed here)
    int base;
    if (qi < 48)       base = (qi - 32) * 3;
    else if (qi < 64)  base = 48 + (qi - 48) * 4;
    else if (qi < 80)  base = 112 + (qi - 64) * 5;
    else if (qi < 96)  base = 192 + (qi - 80) * 6;
    else if (qi < 112) base = 288 + (qi - 96) * 7;
    else               base = 400 + (qi - 112) * 8;
    const size_t slot = (size_t)b * SLOTS_PER_B + base + ck;
    if (lg == 0) {
      pml[slot * 32 + lr] = mrun;
      pml[slot * 32 + 16 + lr] = lrun;
    }
    ushort* ap = &pacc[slot * 2048 + (size_t)lr * 128 + lg * 4];
#pragma unroll
    for (int hf = 0; hf < 8; ++hf) {
      ushort4 u;
      u.x = f2bf(acc[hf][0]); u.y = f2bf(acc[hf][1]);
      u.z = f2bf(acc[hf][2]); u.w = f2bf(acc[hf][3]);
      *(ushort4*)(ap + hf * 16) = u;
    }
  }
}

// ---------------------------------------------------------------------------
// Kernel 2b: online merge of 3..8 partials per (b, qi) for qi >= 32.
// (unchanged from round 8)
// ---------------------------------------------------------------------------
__global__ __launch_bounds__(256) void attn_merge(const float* __restrict__ pml,
                                                  const ushort* __restrict__ pacc,
                                                  float* __restrict__ out) {
  const int bid = blockIdx.x;
  const int b = bid & 7, qi = (bid >> 3) + 32;
  int base, nch;
  if (qi < 48)       { base = (qi - 32) * 3;        nch = 3; }
  else if (qi < 64)  { base = 48 + (qi - 48) * 4;   nch = 4; }
  else if (qi < 80)  { base = 112 + (qi - 64) * 5;  nch = 5; }
  else if (qi < 96)  { base = 192 + (qi - 80) * 6;  nch = 6; }
  else if (qi < 112) { base = 288 + (qi - 96) * 7;  nch = 7; }
  else               { base = 400 + (qi - 112) * 8; nch = 8; }
  const size_t slot0 = (size_t)b * SLOTS_PER_B + base;
  const int tid = threadIdx.x;
  const int r = tid >> 4, c0 = (tid & 15) * 8;

  float mrun = -INFINITY, L = 0.f;
  float o[8];
#pragma unroll
  for (int i = 0; i < 8; ++i) o[i] = 0.f;

  for (int ck = 0; ck < nch; ++ck) {
    const size_t s = slot0 + ck;
    float m = pml[s * 32 + r];
    float l = pml[s * 32 + 16 + r];
    float mn = fmaxf(mrun, m);
    float sc = exp2f(mrun - mn);
    float w  = exp2f(m - mn);
    L = L * sc + w * l;
    const ushort* ap = &pacc[s * 2048 + (size_t)r * 128 + c0];
    ushort4 u0 = *(const ushort4*)ap;
    ushort4 u1 = *(const ushort4*)(ap + 4);
    o[0] = o[0] * sc + w * bf2f(u0.x); o[1] = o[1] * sc + w * bf2f(u0.y);
    o[2] = o[2] * sc + w * bf2f(u0.z); o[3] = o[3] * sc + w * bf2f(u0.w);
    o[4] = o[4] * sc + w * bf2f(u1.x); o[5] = o[5] * sc + w * bf2f(u1.y);
    o[6] = o[6] * sc + w * bf2f(u1.z); o[7] = o[7] * sc + w * bf2f(u1.w);
    mrun = mn;
  }
  float invL = 1.0f / L;
  float4 r0 = make_float4(o[0] * invL, o[1] * invL, o[2] * invL, o[3] * invL);
  float4 r1 = make_float4(o[4] * invL, o[5] * invL, o[6] * invL, o[7] * invL);
  float* op = &out[((size_t)b * T_LEN + qi * 16 + r) * H_DIM + c0];
  *(float4*)op = r0;
  *(float4*)(op + 4) = r1;
}

// ---------------------------------------------------------------------------
// ws layout identical to round 8 (total 30,670,848 B, proven to fit):
//   [0, 786432) wt (dead after qkv_gemm; pml overlaps here, 540,672 B)
//   qws / kws / vtws ; pacc = 8*528 slots * 2048 bf16
// ---------------------------------------------------------------------------
extern "C" void kernel_launch(void* const* d_in, const int* in_sizes, int n_in,
                              void* d_out, int out_size, void* d_ws, size_t ws_size,
                              hipStream_t stream) {
  const float* emb = (const float*)d_in[0];
  const float* Wq  = (const float*)d_in[1];
  const float* Wk  = (const float*)d_in[2];
  const float* Wv  = (const float*)d_in[3];
  float* out = (float*)d_out;

  ushort* wt   = (ushort*)d_ws;
  ushort* qws  = wt  + (size_t)N_COLS * C_DIM;
  ushort* kws  = qws + (size_t)M_ROWS * H_DIM;
  ushort* vtws = kws + (size_t)M_ROWS * H_DIM;
  ushort* pacc = vtws + (size_t)8 * H_DIM * T_LEN;
  float*  pml  = (float*)d_ws;   // overlaps dead wt region

  wt_convert<<<(N_COLS * C_DIM) / 256, 256, 0, stream>>>(Wq, Wk, Wv, wt);
  qkv_gemm<<<(M_ROWS / 32) * 2, 256, 0, stream>>>(emb, wt, qws, kws, vtws);
  attn_part<<<8 * 140, 256, 0, stream>>>(qws, kws, vtws, pml, pacc, out);
  attn_merge<<<8 * 96, 256, 0, stream>>>(pml, pacc, out);
}

// Round 10
// 99.257 us; speedup vs baseline: 1.6892x; 1.0167x over previous
//
#include <hip/hip_runtime.h>
#include <hip/hip_bf16.h>

typedef __bf16 bf16x8 __attribute__((ext_vector_type(8)));
typedef float f32x4 __attribute__((ext_vector_type(4)));
typedef ushort us8 __attribute__((ext_vector_type(8)));

#define MFMA(a, b, c) __builtin_amdgcn_mfma_f32_16x16x32_bf16((a), (b), (c), 0, 0, 0)

static constexpr int T_LEN = 2048;
static constexpr int C_DIM = 1024;
static constexpr int H_DIM = 128;
static constexpr int M_ROWS = 8 * 2048;    // 16384
static constexpr int N_COLS = 384;         // 3 * 128
static constexpr int SLOTS_PER_B = 528;    // partial slots (qi>=32)
static constexpr int PSTR = 72;            // P buffer row stride
static constexpr int KSTR = 136;           // K LDS row stride (272B, 2-way max)
static constexpr int VSTR = 72;            // V LDS row stride (144B, 2-way max)

__device__ __forceinline__ ushort f2bf(float f) {
  union { float f; unsigned u; } v; v.f = f;
  unsigned u = v.u;
  u += 0x7fffu + ((u >> 16) & 1u);
  return (ushort)(u >> 16);
}
__device__ __forceinline__ float bf2f(ushort u) {
  union { unsigned u; float f; } v; v.u = (unsigned)u << 16;
  return v.f;
}

// ---------------------------------------------------------------------------
// Kernel 0: Wq/Wk/Wv fp32 [1024][128] -> bf16 Wt[384][1024] (transposed)
// ---------------------------------------------------------------------------
__global__ void wt_convert(const float* __restrict__ Wq,
                           const float* __restrict__ Wk,
                           const float* __restrict__ Wv,
                           ushort* __restrict__ wt) {
  int flat = blockIdx.x * 256 + threadIdx.x;
  int gc = flat >> 10;
  int c  = flat & 1023;
  int mat = gc >> 7;
  int h   = gc & 127;
  const float* W = (mat == 0) ? Wq : ((mat == 1) ? Wk : Wv);
  wt[flat] = f2bf(W[c * H_DIM + h]);
}

// ---------------------------------------------------------------------------
// Kernel 1: fused QKV projection. Double-buffered LDS for A (X tile) AND
// register ping-pong double-buffer for B (wt fragments): the 6 wt loads for
// iter kt+1 are issued right after iter kt's barrier, consumed next iter —
// breaks the per-iteration L2-latency serial chain (round-9 diagnosis:
// VGPR=40, no ILP, MfmaUtil 7%).
// 256 thr (4 waves), BM=32, BN=192 -> 1024 blocks. Manual 2x unroll with
// named bE/bO sets (static indexing).
// ---------------------------------------------------------------------------
__global__ __launch_bounds__(256, 4) void qkv_gemm(const float* __restrict__ X,
                                                   const ushort* __restrict__ wt,
                                                   ushort* __restrict__ qws,
                                                   ushort* __restrict__ kws,
                                                   ushort* __restrict__ vtws) {
  __shared__ ushort As[2][32 * 64];
  const int tid = threadIdx.x;
  const int wid = tid >> 6, lane = tid & 63;
  const int lg = lane >> 4, lr = lane & 15;
  const int m0 = (blockIdx.x >> 1) * 32;
  const int n0 = (blockIdx.x & 1) * 192;
  const float QSCL = 0.03125f * 1.44269504f;

  const int srow = tid >> 3;
  const int sbyte = ((tid & 7) * 16) ^ ((srow & 7) << 4);
  const float* xrow = &X[(size_t)(m0 + srow) * C_DIM + (tid & 7) * 8];

  // per-column wt base pointers (col c -> gc = n0 + wid*48 + c*16 + lr)
  const ushort* wb0 = &wt[(size_t)(n0 + wid * 48 +  0 + lr) * C_DIM + lg * 8];
  const ushort* wb1 = &wt[(size_t)(n0 + wid * 48 + 16 + lr) * C_DIM + lg * 8];
  const ushort* wb2 = &wt[(size_t)(n0 + wid * 48 + 32 + lr) * C_DIM + lg * 8];

  f32x4 acc[2][3];
#pragma unroll
  for (int r = 0; r < 2; ++r)
#pragma unroll
    for (int c = 0; c < 3; ++c)
      acc[r][c] = f32x4{0.f, 0.f, 0.f, 0.f};

  // prologue: stage X tile 0 into As[0]
  {
    float4 x0 = *(const float4*)&xrow[0];
    float4 x1 = *(const float4*)&xrow[4];
    us8 bv;
    bv[0] = f2bf(x0.x); bv[1] = f2bf(x0.y); bv[2] = f2bf(x0.z); bv[3] = f2bf(x0.w);
    bv[4] = f2bf(x1.x); bv[5] = f2bf(x1.y); bv[6] = f2bf(x1.z); bv[7] = f2bf(x1.w);
    *(us8*)((char*)&As[0][0] + srow * 128 + sbyte) = bv;
  }
  // prologue: B frags for kt=0
  bf16x8 bE[6], bO[6];
#pragma unroll
  for (int ks = 0; ks < 2; ++ks) {
    bE[0 + ks] = *(const bf16x8*)(wb0 + ks * 32);
    bE[2 + ks] = *(const bf16x8*)(wb1 + ks * 32);
    bE[4 + ks] = *(const bf16x8*)(wb2 + ks * 32);
  }

  for (int k2 = 0; k2 < 16; k2 += 2) {
    // ======== even kt = k2 : LDS buf0, consume bE, prefetch bO(k2+1) =====
    float4 xe0 = *(const float4*)&xrow[(k2 + 1) * 64];
    float4 xe1 = *(const float4*)&xrow[(k2 + 1) * 64 + 4];
    __syncthreads();
#pragma unroll
    for (int ks = 0; ks < 2; ++ks) {
      bO[0 + ks] = *(const bf16x8*)(wb0 + (k2 + 1) * 64 + ks * 32);
      bO[2 + ks] = *(const bf16x8*)(wb1 + (k2 + 1) * 64 + ks * 32);
      bO[4 + ks] = *(const bf16x8*)(wb2 + (k2 + 1) * 64 + ks * 32);
    }
    {
      bf16x8 a[2][2];
#pragma unroll
      for (int r = 0; r < 2; ++r)
#pragma unroll
        for (int ks = 0; ks < 2; ++ks) {
          int row = r * 16 + lr;
          int cb = (ks * 64 + lg * 16) ^ ((row & 7) << 4);
          a[r][ks] = *(const bf16x8*)((const char*)&As[0][0] + row * 128 + cb);
        }
#pragma unroll
      for (int c = 0; c < 3; ++c)
#pragma unroll
        for (int ks = 0; ks < 2; ++ks) {
          acc[0][c] = MFMA(a[0][ks], bE[c * 2 + ks], acc[0][c]);
          acc[1][c] = MFMA(a[1][ks], bE[c * 2 + ks], acc[1][c]);
        }
    }
    {
      us8 bv;
      bv[0] = f2bf(xe0.x); bv[1] = f2bf(xe0.y); bv[2] = f2bf(xe0.z); bv[3] = f2bf(xe0.w);
      bv[4] = f2bf(xe1.x); bv[5] = f2bf(xe1.y); bv[6] = f2bf(xe1.z); bv[7] = f2bf(xe1.w);
      *(us8*)((char*)&As[1][0] + srow * 128 + sbyte) = bv;
    }

    // ======== odd kt = k2+1 : LDS buf1, consume bO, prefetch bE(k2+2) ====
    const bool more = (k2 + 2) < 16;
    float4 xo0, xo1;
    if (more) {
      xo0 = *(const float4*)&xrow[(k2 + 2) * 64];
      xo1 = *(const float4*)&xrow[(k2 + 2) * 64 + 4];
    }
    __syncthreads();
    if (more) {
#pragma unroll
      for (int ks = 0; ks < 2; ++ks) {
        bE[0 + ks] = *(const bf16x8*)(wb0 + (k2 + 2) * 64 + ks * 32);
        bE[2 + ks] = *(const bf16x8*)(wb1 + (k2 + 2) * 64 + ks * 32);
        bE[4 + ks] = *(const bf16x8*)(wb2 + (k2 + 2) * 64 + ks * 32);
      }
    }
    {
      bf16x8 a[2][2];
#pragma unroll
      for (int r = 0; r < 2; ++r)
#pragma unroll
        for (int ks = 0; ks < 2; ++ks) {
          int row = r * 16 + lr;
          int cb = (ks * 64 + lg * 16) ^ ((row & 7) << 4);
          a[r][ks] = *(const bf16x8*)((const char*)&As[1][0] + row * 128 + cb);
        }
#pragma unroll
      for (int c = 0; c < 3; ++c)
#pragma unroll
        for (int ks = 0; ks < 2; ++ks) {
          acc[0][c] = MFMA(a[0][ks], bO[c * 2 + ks], acc[0][c]);
          acc[1][c] = MFMA(a[1][ks], bO[c * 2 + ks], acc[1][c]);
        }
    }
    if (more) {
      us8 bv;
      bv[0] = f2bf(xo0.x); bv[1] = f2bf(xo0.y); bv[2] = f2bf(xo0.z); bv[3] = f2bf(xo0.w);
      bv[4] = f2bf(xo1.x); bv[5] = f2bf(xo1.y); bv[6] = f2bf(xo1.z); bv[7] = f2bf(xo1.w);
      *(us8*)((char*)&As[0][0] + srow * 128 + sbyte) = bv;
    }
  }

  // epilogue: C frag layout col=lane&15, row=(lane>>4)*4+j
#pragma unroll
  for (int c = 0; c < 3; ++c) {
    int gc = n0 + wid * 48 + c * 16 + lr;
    int mat = gc >> 7, h = gc & 127;
#pragma unroll
    for (int r = 0; r < 2; ++r) {
#pragma unroll
      for (int j = 0; j < 4; ++j) {
        int gr = m0 + r * 16 + lg * 4 + j;
        float val = acc[r][c][j];
        ushort ov = f2bf(mat == 0 ? val * QSCL : val);
        if (mat == 0) {
          qws[(size_t)gr * H_DIM + h] = ov;
        } else if (mat == 1) {
          kws[(size_t)gr * H_DIM + h] = ov;
        } else {
          int b = gr >> 11, t = gr & 2047;
          vtws[((size_t)b * H_DIM + h) * T_LEN + t] = ov;
        }
      }
    }
  }
}

// ---------------------------------------------------------------------------
// Kernel 2a: flash partial pass, block-cooperative LDS-staged K/V
// (unchanged from round 9).
// ---------------------------------------------------------------------------
__global__ __launch_bounds__(256, 3) void attn_part(const ushort* __restrict__ qws,
                                                    const ushort* __restrict__ kws,
                                                    const ushort* __restrict__ vtws,
                                                    float* __restrict__ pml,
                                                    ushort* __restrict__ pacc,
                                                    float* __restrict__ out) {
  __shared__ ushort Klds[64 * KSTR];
  __shared__ ushort Vlds[128 * VSTR];
  __shared__ ushort Pw[4][16 * PSTR];

  const int tid = threadIdx.x;
  const int wid = tid >> 6, lane = tid & 63;
  const int lg = lane >> 4, lr = lane & 15;
  const int bid = blockIdx.x;
  const int b = bid & 7;
  const int item = bid >> 3;

  int qb, ck;
  bool direct;
  if (item < 8) {
    qb = item; ck = 0; direct = true;
  } else {
    const int p = item - 8;
    direct = false;
    if (p < 12)      { int q = p / 3;        qb = 8 + q;  ck = p - q * 3; }
    else if (p < 28) { int q = (p - 12) >> 2; qb = 12 + q; ck = (p - 12) & 3; }
    else if (p < 48) { int q = (p - 28) / 5; qb = 16 + q; ck = (p - 28) - q * 5; }
    else if (p < 72) { int q = (p - 48) / 6; qb = 20 + q; ck = (p - 48) - q * 6; }
    else if (p < 100){ int q = (p - 72) / 7; qb = 24 + q; ck = (p - 72) - q * 7; }
    else             { int q = (p - 100) >> 3; qb = 28 + q; ck = (p - 100) & 7; }
  }
  const int qi = qb * 4 + wid;
  const int q0 = qi * 16;
  const int nt = qb + 1;
  const int kvt_lo = direct ? 0 : ck * 4;
  const int kvt_hi = direct ? nt : min(ck * 4 + 4, nt);
  const size_t tokbase = (size_t)b * T_LEN;
  const ushort* vb = vtws + (size_t)b * H_DIM * T_LEN;

  const int kr = tid >> 2, kseg = tid & 3;
  const int vr = tid >> 1, vseg = tid & 1;
  const ushort* gK = &kws[(tokbase + kr) * H_DIM + kseg * 32];
  const ushort* gV = &vb[(size_t)vr * T_LEN + vseg * 32];

  bf16x8 qf[4];
#pragma unroll
  for (int hk = 0; hk < 4; ++hk)
    qf[hk] = *(const bf16x8*)&qws[(tokbase + q0 + lr) * H_DIM + hk * 32 + lg * 8];

  f32x4 acc[8];
#pragma unroll
  for (int hf = 0; hf < 8; ++hf) acc[hf] = f32x4{0.f, 0.f, 0.f, 0.f};
  float mrun = -INFINITY, lrun = 0.f;

  ushort* Pme = &Pw[wid][0];

  us8 kreg[4], vreg[4];
#pragma unroll
  for (int i = 0; i < 4; ++i) {
    kreg[i] = *(const us8*)(gK + (size_t)kvt_lo * 64 * H_DIM + i * 8);
    vreg[i] = *(const us8*)(gV + kvt_lo * 64 + i * 8);
  }

  for (int kvt = kvt_lo; kvt < kvt_hi; ++kvt) {
    const int kv0 = kvt * 64;

    __syncthreads();
#pragma unroll
    for (int i = 0; i < 4; ++i) {
      *(us8*)&Klds[kr * KSTR + kseg * 32 + i * 8] = kreg[i];
      *(us8*)&Vlds[vr * VSTR + vseg * 32 + i * 8] = vreg[i];
    }
    if (kvt + 1 < kvt_hi) {
#pragma unroll
      for (int i = 0; i < 4; ++i) {
        kreg[i] = *(const us8*)(gK + (size_t)(kv0 + 64) * H_DIM + i * 8);
        vreg[i] = *(const us8*)(gV + kv0 + 64 + i * 8);
      }
    }
    __syncthreads();

    f32x4 s[4];
#pragma unroll
    for (int c = 0; c < 4; ++c) {
      f32x4 sc = f32x4{0.f, 0.f, 0.f, 0.f};
#pragma unroll
      for (int hk = 0; hk < 4; ++hk) {
        bf16x8 kf = *(const bf16x8*)&Klds[(c * 16 + lr) * KSTR + hk * 32 + lg * 8];
        sc = MFMA(kf, qf[hk], sc);
      }
      s[c] = sc;
    }

    if (kvt == nt - 1) {
#pragma unroll
      for (int c = 0; c < 4; ++c)
#pragma unroll
        for (int j = 0; j < 4; ++j) {
          int kv = kv0 + c * 16 + lg * 4 + j;
          if (kv > q0 + lr) s[c][j] = -INFINITY;
        }
    }

    float mx = s[0][0];
#pragma unroll
    for (int c = 0; c < 4; ++c)
#pragma unroll
      for (int j = 0; j < 4; ++j) mx = fmaxf(mx, s[c][j]);
    mx = fmaxf(mx, __shfl_xor(mx, 16));
    mx = fmaxf(mx, __shfl_xor(mx, 32));

    float mnew = fmaxf(mrun, mx);
    float scold = exp2f(mrun - mnew);

    float rsum = 0.f;
#pragma unroll
    for (int c = 0; c < 4; ++c)
#pragma unroll
      for (int j = 0; j < 4; ++j) {
        float p = exp2f(s[c][j] - mnew);
        s[c][j] = p;
        rsum += p;
      }

#pragma unroll
    for (int c = 0; c < 4; ++c) {
      ushort4 u;
      u.x = f2bf(s[c][0]); u.y = f2bf(s[c][1]);
      u.z = f2bf(s[c][2]); u.w = f2bf(s[c][3]);
      *(ushort4*)&Pme[lr * PSTR + c * 16 + lg * 4] = u;
    }

    bf16x8 v0[8];
#pragma unroll
    for (int hf = 0; hf < 8; ++hf)
      v0[hf] = *(const bf16x8*)&Vlds[(hf * 16 + lr) * VSTR + lg * 8];

    rsum += __shfl_xor(rsum, 16);
    rsum += __shfl_xor(rsum, 32);

    lrun = lrun * scold + rsum;
    mrun = mnew;
#pragma unroll
    for (int hf = 0; hf < 8; ++hf)
#pragma unroll
      for (int j = 0; j < 4; ++j) acc[hf][j] *= scold;

    bf16x8 pa0 = *(const bf16x8*)&Pme[lr * PSTR + lg * 8];
    bf16x8 pa1 = *(const bf16x8*)&Pme[lr * PSTR + 32 + lg * 8];

#pragma unroll
    for (int hf = 0; hf < 8; ++hf)
      acc[hf] = MFMA(v0[hf], pa0, acc[hf]);
#pragma unroll
    for (int hf = 0; hf < 8; ++hf) {
      bf16x8 v1 = *(const bf16x8*)&Vlds[(hf * 16 + lr) * VSTR + 32 + lg * 8];
      acc[hf] = MFMA(v1, pa1, acc[hf]);
    }
  }

  if (direct) {
    float inv = 1.0f / lrun;
    float* op = &out[(tokbase + q0 + lr) * H_DIM + lg * 4];
#pragma unroll
    for (int hf = 0; hf < 8; ++hf) {
      float4 r0 = make_float4(acc[hf][0] * inv, acc[hf][1] * inv,
                              acc[hf][2] * inv, acc[hf][3] * inv);
      *(float4*)(op + hf * 16) = r0;
    }
  } else {
    int base;
    if (qi < 48)       base = (qi - 32) * 3;
    else if (qi < 64)  base = 48 + (qi - 48) * 4;
    else if (qi < 80)  base = 112 + (qi - 64) * 5;
    else if (qi < 96)  base = 192 + (qi - 80) * 6;
    else if (qi < 112) base = 288 + (qi - 96) * 7;
    else               base = 400 + (qi - 112) * 8;
    const size_t slot = (size_t)b * SLOTS_PER_B + base + ck;
    if (lg == 0) {
      pml[slot * 32 + lr] = mrun;
      pml[slot * 32 + 16 + lr] = lrun;
    }
    ushort* ap = &pacc[slot * 2048 + (size_t)lr * 128 + lg * 4];
#pragma unroll
    for (int hf = 0; hf < 8; ++hf) {
      ushort4 u;
      u.x = f2bf(acc[hf][0]); u.y = f2bf(acc[hf][1]);
      u.z = f2bf(acc[hf][2]); u.w = f2bf(acc[hf][3]);
      *(ushort4*)(ap + hf * 16) = u;
    }
  }
}

// ---------------------------------------------------------------------------
// Kernel 2b: online merge of 3..8 partials per (b, qi) for qi >= 32.
// (unchanged)
// ---------------------------------------------------------------------------
__global__ __launch_bounds__(256) void attn_merge(const float* __restrict__ pml,
                                                  const ushort* __restrict__ pacc,
                                                  float* __restrict__ out) {
  const int bid = blockIdx.x;
  const int b = bid & 7, qi = (bid >> 3) + 32;
  int base, nch;
  if (qi < 48)       { base = (qi - 32) * 3;        nch = 3; }
  else if (qi < 64)  { base = 48 + (qi - 48) * 4;   nch = 4; }
  else if (qi < 80)  { base = 112 + (qi - 64) * 5;  nch = 5; }
  else if (qi < 96)  { base = 192 + (qi - 80) * 6;  nch = 6; }
  else if (qi < 112) { base = 288 + (qi - 96) * 7;  nch = 7; }
  else               { base = 400 + (qi - 112) * 8; nch = 8; }
  const size_t slot0 = (size_t)b * SLOTS_PER_B + base;
  const int tid = threadIdx.x;
  const int r = tid >> 4, c0 = (tid & 15) * 8;

  float mrun = -INFINITY, L = 0.f;
  float o[8];
#pragma unroll
  for (int i = 0; i < 8; ++i) o[i] = 0.f;

  for (int ck = 0; ck < nch; ++ck) {
    const size_t s = slot0 + ck;
    float m = pml[s * 32 + r];
    float l = pml[s * 32 + 16 + r];
    float mn = fmaxf(mrun, m);
    float sc = exp2f(mrun - mn);
    float w  = exp2f(m - mn);
    L = L * sc + w * l;
    const ushort* ap = &pacc[s * 2048 + (size_t)r * 128 + c0];
    ushort4 u0 = *(const ushort4*)ap;
    ushort4 u1 = *(const ushort4*)(ap + 4);
    o[0] = o[0] * sc + w * bf2f(u0.x); o[1] = o[1] * sc + w * bf2f(u0.y);
    o[2] = o[2] * sc + w * bf2f(u0.z); o[3] = o[3] * sc + w * bf2f(u0.w);
    o[4] = o[4] * sc + w * bf2f(u1.x); o[5] = o[5] * sc + w * bf2f(u1.y);
    o[6] = o[6] * sc + w * bf2f(u1.z); o[7] = o[7] * sc + w * bf2f(u1.w);
    mrun = mn;
  }
  float invL = 1.0f / L;
  float4 r0 = make_float4(o[0] * invL, o[1] * invL, o[2] * invL, o[3] * invL);
  float4 r1 = make_float4(o[4] * invL, o[5] * invL, o[6] * invL, o[7] * invL);
  float* op = &out[((size_t)b * T_LEN + qi * 16 + r) * H_DIM + c0];
  *(float4*)op = r0;
  *(float4*)(op + 4) = r1;
}

// ---------------------------------------------------------------------------
// ws layout identical to rounds 8/9 (total 30,670,848 B, proven fit):
//   [0, 786432) wt (dead after qkv_gemm; pml overlaps, 540,672 B)
//   qws / kws / vtws ; pacc = 8*528 slots * 2048 bf16
// ---------------------------------------------------------------------------
extern "C" void kernel_launch(void* const* d_in, const int* in_sizes, int n_in,
                              void* d_out, int out_size, void* d_ws, size_t ws_size,
                              hipStream_t stream) {
  const float* emb = (const float*)d_in[0];
  const float* Wq  = (const float*)d_in[1];
  const float* Wk  = (const float*)d_in[2];
  const float* Wv  = (const float*)d_in[3];
  float* out = (float*)d_out;

  ushort* wt   = (ushort*)d_ws;
  ushort* qws  = wt  + (size_t)N_COLS * C_DIM;
  ushort* kws  = qws + (size_t)M_ROWS * H_DIM;
  ushort* vtws = kws + (size_t)M_ROWS * H_DIM;
  ushort* pacc = vtws + (size_t)8 * H_DIM * T_LEN;
  float*  pml  = (float*)d_ws;   // overlaps dead wt region

  wt_convert<<<(N_COLS * C_DIM) / 256, 256, 0, stream>>>(Wq, Wk, Wv, wt);
  qkv_gemm<<<(M_ROWS / 32) * 2, 256, 0, stream>>>(emb, wt, qws, kws, vtws);
  attn_part<<<8 * 140, 256, 0, stream>>>(qws, kws, vtws, pml, pacc, out);
  attn_merge<<<8 * 96, 256, 0, stream>>>(pml, pacc, out);
}